// Round 12
// baseline (837.590 us; speedup 1.0000x reference)
//
#include <hip/hip_runtime.h>
#include <cstddef>

// Problem constants (from reference setup_inputs)
static constexpr int NN   = 100000;   // nodes
static constexpr int NE   = 3200000;  // edges
static constexpr int CIN  = 512;
static constexpr int CHID = 40;
static constexpr int COUT = 20;
static constexpr int NB   = 64;              // private counter copies
static constexpr int CHUNK = NE / NB;        // 50000 edges per copy (divisible by 4)

// clang native vector type: required by __builtin_nontemporal_load
// (HIP float4 is a class type and is rejected -- R9 compile error).
typedef float f32x4 __attribute__((ext_vector_type(4)));

// ---------------- CSR build ----------------

// R11 profile: old k_count = 149us, VALUBusy 0.24%, WRITE_SIZE 112MB --
// device-scope atomics bypass the (non-coherent) per-XCD L2 and execute
// memory-side: every atomicAdd = one 32B TCC transaction. Fix: 64
// block-private counter copies + WORKGROUP-scope atomics (legal: single
// block owns each copy) -> atomics stay in the local XCD L2 (8 copies x
// 400KB = 3.2MB per XCD L2). rank[e] = local rank within the block copy.
__global__ __launch_bounds__(1024) void k_countP(const int* __restrict__ dst, int* __restrict__ cntb,
                                                 int* __restrict__ rank) {
  const int b = blockIdx.x;                    // 0..63
  int* __restrict__ cb = cntb + (size_t)b * NN;
  const int base = b * (CHUNK / 4);            // int4 units
  const int end  = base + CHUNK / 4;
  for (int i = base + (int)threadIdx.x; i < end; i += 1024) {
    const int4 d = ((const int4*)dst)[i];
    int4 r;
    r.x = __hip_atomic_fetch_add(&cb[d.x], 1, __ATOMIC_RELAXED, __HIP_MEMORY_SCOPE_WORKGROUP);
    r.y = __hip_atomic_fetch_add(&cb[d.y], 1, __ATOMIC_RELAXED, __HIP_MEMORY_SCOPE_WORKGROUP);
    r.z = __hip_atomic_fetch_add(&cb[d.z], 1, __ATOMIC_RELAXED, __HIP_MEMORY_SCOPE_WORKGROUP);
    r.w = __hip_atomic_fetch_add(&cb[d.w], 1, __ATOMIC_RELAXED, __HIP_MEMORY_SCOPE_WORKGROUP);
    ((int4*)rank)[i] = r;
  }
}

// per node: turn the 64 copies into an exclusive prefix across copies
// (in place) and emit the total count. Coalesced: consecutive i per lane.
__global__ __launch_bounds__(256) void k_merge(int* __restrict__ cntb, int* __restrict__ cnt, int n) {
  const int i = blockIdx.x * 256 + threadIdx.x;
  if (i >= n) return;
  int s = 0;
#pragma unroll 8
  for (int b = 0; b < NB; ++b) {
    int* p = cntb + (size_t)b * NN + i;
    const int t = *p;
    *p = s;
    s += t;
  }
  cnt[i] = s;
}

// fallback (ws too small): original device-scope atomic count.
__global__ __launch_bounds__(256) void k_count(const int* __restrict__ dst, int* __restrict__ cnt,
                                               int* __restrict__ rank, int n_edges4) {
  const int e4 = blockIdx.x * 256 + threadIdx.x;
  if (e4 >= n_edges4) return;
  const int4 d = ((const int4*)dst)[e4];
  int4 r;
  r.x = atomicAdd(&cnt[d.x], 1);
  r.y = atomicAdd(&cnt[d.y], 1);
  r.z = atomicAdd(&cnt[d.z], 1);
  r.w = atomicAdd(&cnt[d.w], 1);
  ((int4*)rank)[e4] = r;
}

// block of 256 scans 1024 elements; writes per-element exclusive scan (within block),
// block totals, and fused dinv = rsqrt(deg) = rsqrt(cnt+1).
__global__ __launch_bounds__(256) void k_scanA(const int* __restrict__ cnt, int* __restrict__ excl,
                                               int* __restrict__ bsums, float* __restrict__ dinv, int n) {
  __shared__ int sdata[256];
  const int t = threadIdx.x;
  const int base = blockIdx.x * 1024 + t * 4;
  int v[4];
#pragma unroll
  for (int j = 0; j < 4; ++j) {
    const int i = base + j;
    v[j] = (i < n) ? cnt[i] : 0;
    if (i < n) dinv[i] = rsqrtf((float)(v[j] + 1));
  }
  const int s4 = v[0] + v[1] + v[2] + v[3];
  sdata[t] = s4;
  __syncthreads();
  for (int off = 1; off < 256; off <<= 1) {
    int val = 0;
    if (t >= off) val = sdata[t - off];
    __syncthreads();
    sdata[t] += val;
    __syncthreads();
  }
  int run = sdata[t] - s4;  // exclusive prefix of this thread's 4 items
#pragma unroll
  for (int j = 0; j < 4; ++j) {
    const int i = base + j;
    if (i < n) excl[i] = run;
    run += v[j];
  }
  if (t == 255) bsums[blockIdx.x] = sdata[255];
}

__global__ __launch_bounds__(256) void k_scanB(int* __restrict__ bsums, int nb) {
  __shared__ int sdata[256];
  const int t = threadIdx.x;
  const int v = (t < nb) ? bsums[t] : 0;
  sdata[t] = v;
  __syncthreads();
  for (int off = 1; off < 256; off <<= 1) {
    int val = 0;
    if (t >= off) val = sdata[t - off];
    __syncthreads();
    sdata[t] += val;
    __syncthreads();
  }
  if (t < nb) bsums[t] = sdata[t] - v;  // exclusive, in place
}

__global__ __launch_bounds__(256) void k_scanC(int* __restrict__ rowptr, const int* __restrict__ boff,
                                               int n, int n_edges) {
  const int i = blockIdx.x * 256 + threadIdx.x;
  if (i < n) rowptr[i] += boff[i >> 10];
  if (i == 0) rowptr[n] = n_edges;
}

// gather + scattered 4B writes; pos = rowptr[d] + cross-copy offset + local rank.
__global__ __launch_bounds__(256) void k_fillP(const int* __restrict__ src, const int* __restrict__ dst,
                                               const int* __restrict__ rank, const int* __restrict__ rowptr,
                                               const int* __restrict__ cntb, int* __restrict__ csr_src,
                                               int n_edges4) {
  const int e4 = blockIdx.x * 256 + threadIdx.x;
  if (e4 >= n_edges4) return;
  const int4 s = ((const int4*)src)[e4];
  const int4 d = ((const int4*)dst)[e4];
  const int4 r = ((const int4*)rank)[e4];
  const int b = (e4 * 4) / CHUNK;  // chunk id (CHUNK%4==0 -> all 4 same chunk)
  const int* __restrict__ cb = cntb + (size_t)b * NN;
  csr_src[rowptr[d.x] + cb[d.x] + r.x] = s.x;
  csr_src[rowptr[d.y] + cb[d.y] + r.y] = s.y;
  csr_src[rowptr[d.z] + cb[d.z] + r.z] = s.z;
  csr_src[rowptr[d.w] + cb[d.w] + r.w] = s.w;
}

// fallback fill (global-rank semantics of old k_count).
__global__ __launch_bounds__(256) void k_fill(const int* __restrict__ src, const int* __restrict__ dst,
                                              const int* __restrict__ rank, const int* __restrict__ rowptr,
                                              int* __restrict__ csr_src, int n_edges4) {
  const int e4 = blockIdx.x * 256 + threadIdx.x;
  if (e4 >= n_edges4) return;
  const int4 s = ((const int4*)src)[e4];
  const int4 d = ((const int4*)dst)[e4];
  const int4 r = ((const int4*)rank)[e4];
  csr_src[rowptr[d.x] + r.x] = s.x;
  csr_src[rowptr[d.y] + r.y] = s.y;
  csr_src[rowptr[d.z] + r.z] = s.z;
  csr_src[rowptr[d.w] + r.w] = s.w;
}

// ---------------- GEMM 1: NT loads + software-pipelined staging ----------------
// R11 confirmed the NT-load theory (WRITE 215.6 -> 15.6MB, 228 -> 147us).
// Residual: VALU work ~31us of 147 -> still stalled; loads for tile kt
// issue only after compute(kt-1) retires. This version issues the NT loads
// for kt+1 BEFORE compute(kt) -- in flight across the full 1280-cycle
// compute block -- then {barrier; ds_write; barrier}. Indexing, swizzle,
// wave-uniform g=t>>6, and summation order identical to R11 (absmax 4.88e-4).
__global__ __launch_bounds__(256) void k_gemm1(const float* __restrict__ x, const float* __restrict__ W,
                                               float* __restrict__ h, int n) {
  __shared__ float xt[64 * 128];  // 32 KB; reused as output staging [64][44]
  const int t  = threadIdx.x;
  const int nd = t & 63;                                   // node-in-tile (compute)
  const int g  = __builtin_amdgcn_readfirstlane(t >> 6);   // channel group 0..3 (wave-uniform)
  const int block0 = blockIdx.x * 64;

  // staging map: idx = r*256 + t -> row = idx>>5, float4-col = idx&31
  const int sn = t >> 5;   // rows sn, sn+8, ..., sn+56
  const int c4 = t & 31;

  float acc[10];
#pragma unroll
  for (int j = 0; j < 10; ++j) acc[j] = 0.f;

  f32x4 v[8];
  // prologue: stage tile 0
#pragma unroll
  for (int r = 0; r < 8; ++r) {
    const int row = r * 8 + sn;
    int gn = block0 + row;
    if (gn >= n) gn = n - 1;  // clamp: valid memory, store is guarded
    v[r] = __builtin_nontemporal_load(((const f32x4*)(x + (size_t)gn * CIN)) + c4);
  }
#pragma unroll
  for (int r = 0; r < 8; ++r) {
    const int row = r * 8 + sn;
    const int byte = row * 512 + ((c4 * 16) ^ ((row & 31) << 4));
    *(f32x4*)((char*)xt + byte) = v[r];
  }
  __syncthreads();  // tile 0 ready

  for (int kt = 0; kt < 4; ++kt) {
    if (kt < 3) {  // issue next tile's loads NOW; they fly during compute(kt)
#pragma unroll
      for (int r = 0; r < 8; ++r) {
        const int row = r * 8 + sn;
        int gn = block0 + row;
        if (gn >= n) gn = n - 1;
        v[r] = __builtin_nontemporal_load(
            ((const f32x4*)(x + (size_t)gn * CIN + (kt + 1) * 128)) + c4);
      }
    }

    // ---- compute: 128 k-values, 10 channels per thread
    const float* __restrict__ Wg = W + (size_t)kt * 128 * CHID + g * 10;
#pragma unroll 4
    for (int k4 = 0; k4 < 32; ++k4) {
      const int byte = nd * 512 + ((k4 * 16) ^ ((nd & 31) << 4));
      const f32x4 xv = *(const f32x4*)((const char*)xt + byte);
      const float* __restrict__ Wk = Wg + k4 * 4 * CHID;
#pragma unroll
      for (int j = 0; j < 10; ++j) acc[j] = fmaf(xv.x, Wk[j], acc[j]);
#pragma unroll
      for (int j = 0; j < 10; ++j) acc[j] = fmaf(xv.y, Wk[CHID + j], acc[j]);
#pragma unroll
      for (int j = 0; j < 10; ++j) acc[j] = fmaf(xv.z, Wk[2 * CHID + j], acc[j]);
#pragma unroll
      for (int j = 0; j < 10; ++j) acc[j] = fmaf(xv.w, Wk[3 * CHID + j], acc[j]);
    }

    if (kt < 3) {
      __syncthreads();  // all waves done reading tile kt
#pragma unroll
      for (int r = 0; r < 8; ++r) {
        const int row = r * 8 + sn;
        const int byte = row * 512 + ((c4 * 16) ^ ((row & 31) << 4));
        *(f32x4*)((char*)xt + byte) = v[r];
      }
      __syncthreads();  // tile kt+1 ready
    }
  }

  // ---- coalesced epilogue through LDS ----
  __syncthreads();  // all waves done reading xt
#pragma unroll
  for (int j = 0; j < 10; ++j) xt[nd * 44 + g * 10 + j] = acc[j];
  __syncthreads();
  // 64 rows x 40 floats = 640 float4, contiguous across the block's h region
  for (int i = t; i < 640; i += 256) {
    const int row = i / 10;
    const int c   = i % 10;
    const int node = block0 + row;
    if (node < n)
      ((float4*)(h + (size_t)node * CHID))[c] = *(const float4*)&xt[row * 44 + c * 4];
  }
}

__global__ __launch_bounds__(256) void k_gemm2(const float* __restrict__ t1, const float* __restrict__ W,
                                               float* __restrict__ g, int n) {
  const int node = blockIdx.x * 256 + threadIdx.x;
  if (node >= n) return;
  const float4* __restrict__ r4 = (const float4*)(t1 + (size_t)node * CHID);
  float acc[COUT];
#pragma unroll
  for (int c = 0; c < COUT; ++c) acc[c] = 0.f;
#pragma unroll
  for (int kk = 0; kk < CHID / 4; ++kk) {
    const float4 xv = r4[kk];
    const float* __restrict__ Wk = W + kk * 4 * COUT;
#pragma unroll
    for (int c = 0; c < COUT; ++c) {
      float a = acc[c];
      a = fmaf(xv.x, Wk[c], a);
      a = fmaf(xv.y, Wk[COUT + c], a);
      a = fmaf(xv.z, Wk[2 * COUT + c], a);
      a = fmaf(xv.w, Wk[3 * COUT + c], a);
      acc[c] = a;
    }
  }
  float* __restrict__ o = g + (size_t)node * COUT;
#pragma unroll
  for (int c = 0; c < COUT; ++c) o[c] = acc[c];
}

// ---------------- CSR aggregation ----------------
// Layer 1 (CH=40): float2 channel-packing — 20 lanes/node, 3 nodes/wave.
__global__ __launch_bounds__(256) void k_agg40(const float* __restrict__ h, const int* __restrict__ rowptr,
                                               const int* __restrict__ csr_src, const float* __restrict__ dinv,
                                               const float* __restrict__ bias, float* __restrict__ out, int n) {
  const int wave = (blockIdx.x * 256 + (int)threadIdx.x) >> 6;
  const int lane = threadIdx.x & 63;
  const int sub  = lane / 20;   // 0..2 active; 3 => idle lanes 60..63
  const int cp   = lane % 20;   // channel pair: channels {2cp, 2cp+1}
  const int node = wave * 3 + sub;
  if (sub >= 3 || node >= n) return;
  const float2* __restrict__ h2 = (const float2*)h;
  const int r0 = rowptr[node];
  const int r1 = rowptr[node + 1];
  const float dv = dinv[node];
  const float self_w = dv * dv;  // self-loop norm = 1/deg
  float2 acc = h2[(size_t)node * 20 + cp];
  acc.x *= self_w;
  acc.y *= self_w;
  int i = r0;
  for (; i + 4 <= r1; i += 4) {
    const int s0 = csr_src[i + 0];
    const int s1 = csr_src[i + 1];
    const int s2 = csr_src[i + 2];
    const int s3 = csr_src[i + 3];
    const float w0 = dinv[s0] * dv;
    const float w1 = dinv[s1] * dv;
    const float w2 = dinv[s2] * dv;
    const float w3 = dinv[s3] * dv;
    const float2 g0 = h2[(size_t)s0 * 20 + cp];
    const float2 g1 = h2[(size_t)s1 * 20 + cp];
    const float2 g2 = h2[(size_t)s2 * 20 + cp];
    const float2 g3 = h2[(size_t)s3 * 20 + cp];
    acc.x = fmaf(g0.x, w0, acc.x); acc.y = fmaf(g0.y, w0, acc.y);
    acc.x = fmaf(g1.x, w1, acc.x); acc.y = fmaf(g1.y, w1, acc.y);
    acc.x = fmaf(g2.x, w2, acc.x); acc.y = fmaf(g2.y, w2, acc.y);
    acc.x = fmaf(g3.x, w3, acc.x); acc.y = fmaf(g3.y, w3, acc.y);
  }
  for (; i < r1; ++i) {
    const int s = csr_src[i];
    const float w = dinv[s] * dv;
    const float2 g = h2[(size_t)s * 20 + cp];
    acc.x = fmaf(g.x, w, acc.x);
    acc.y = fmaf(g.y, w, acc.y);
  }
  const float2 bv = ((const float2*)bias)[cp];
  float2 v;
  v.x = fmaxf(acc.x + bv.x, 0.f);  // ReLU (layer 1 only)
  v.y = fmaxf(acc.y + bv.y, 0.f);
  ((float2*)out)[(size_t)node * 20 + cp] = v;
}

// Layer 2 (CH=20): float2 packing — 10 lanes/node, 6 nodes/wave.
__global__ __launch_bounds__(256) void k_agg20(const float* __restrict__ h, const int* __restrict__ rowptr,
                                               const int* __restrict__ csr_src, const float* __restrict__ dinv,
                                               const float* __restrict__ bias, float* __restrict__ out, int n) {
  const int wave = (blockIdx.x * 256 + (int)threadIdx.x) >> 6;
  const int lane = threadIdx.x & 63;
  const int sub  = lane / 10;   // 0..5 active; 6 => idle lanes 60..63
  const int cp   = lane % 10;   // channel pair: channels {2cp, 2cp+1}
  const int node = wave * 6 + sub;
  if (sub >= 6 || node >= n) return;
  const float2* __restrict__ h2 = (const float2*)h;
  const int r0 = rowptr[node];
  const int r1 = rowptr[node + 1];
  const float dv = dinv[node];
  const float self_w = dv * dv;
  float2 acc = h2[(size_t)node * 10 + cp];
  acc.x *= self_w;
  acc.y *= self_w;
  int i = r0;
  for (; i + 4 <= r1; i += 4) {
    const int s0 = csr_src[i + 0];
    const int s1 = csr_src[i + 1];
    const int s2 = csr_src[i + 2];
    const int s3 = csr_src[i + 3];
    const float w0 = dinv[s0] * dv;
    const float w1 = dinv[s1] * dv;
    const float w2 = dinv[s2] * dv;
    const float w3 = dinv[s3] * dv;
    const float2 g0 = h2[(size_t)s0 * 10 + cp];
    const float2 g1 = h2[(size_t)s1 * 10 + cp];
    const float2 g2 = h2[(size_t)s2 * 10 + cp];
    const float2 g3 = h2[(size_t)s3 * 10 + cp];
    acc.x = fmaf(g0.x, w0, acc.x); acc.y = fmaf(g0.y, w0, acc.y);
    acc.x = fmaf(g1.x, w1, acc.x); acc.y = fmaf(g1.y, w1, acc.y);
    acc.x = fmaf(g2.x, w2, acc.x); acc.y = fmaf(g2.y, w2, acc.y);
    acc.x = fmaf(g3.x, w3, acc.x); acc.y = fmaf(g3.y, w3, acc.y);
  }
  for (; i < r1; ++i) {
    const int s = csr_src[i];
    const float w = dinv[s] * dv;
    const float2 g = h2[(size_t)s * 10 + cp];
    acc.x = fmaf(g.x, w, acc.x);
    acc.y = fmaf(g.y, w, acc.y);
  }
  const float2 bv = ((const float2*)bias)[cp];
  float2 v;
  v.x = acc.x + bv.x;
  v.y = acc.y + bv.y;
  ((float2*)out)[(size_t)node * 10 + cp] = v;
}

// ---------------- launch ----------------

extern "C" void kernel_launch(void* const* d_in, const int* in_sizes, int n_in,
                              void* d_out, int out_size, void* d_ws, size_t ws_size,
                              hipStream_t stream) {
  const float* x   = (const float*)d_in[0];
  const int*   ei  = (const int*)d_in[1];
  const float* W1  = (const float*)d_in[2];
  const float* b1  = (const float*)d_in[3];
  const float* W2  = (const float*)d_in[4];
  const float* b2  = (const float*)d_in[5];
  float* out = (float*)d_out;

  const int* srcp = ei;        // edge_index[0]
  const int* dstp = ei + NE;   // edge_index[1]

  // workspace layout (~85 MB with cntb; guarded fallback if ws too small)
  char* ws = (char*)d_ws;
  size_t off = 0;
  auto take = [&](size_t bytes) -> char* {
    char* p = ws + off;
    off = (off + bytes + 255) & ~(size_t)255;
    return p;
  };
  int*   cnt     = (int*)take((size_t)NN * 4);
  int*   rowptr  = (int*)take((size_t)(NN + 1) * 4);
  float* dinv    = (float*)take((size_t)NN * 4);
  int*   bsums   = (int*)take(256 * 4);
  int*   rank    = (int*)take((size_t)NE * 4);
  int*   csr_src = (int*)take((size_t)NE * 4);
  float* h1      = (float*)take((size_t)NN * CHID * 4);
  float* t1      = (float*)take((size_t)NN * CHID * 4);
  float* g2      = h1;  // h1 dead after agg1; reuse for layer-2 GEMM output
  const size_t base_need = off;
  int*   cntb    = (int*)take((size_t)NB * NN * 4);  // 25.6 MB private copies
  const bool privatized = (ws_size >= off);

  (void)in_sizes; (void)n_in; (void)out_size;

  const int ne4 = NE / 4;  // 800000
  const int nb = (NN + 1023) / 1024;  // 98

  if (privatized) {
    hipMemsetAsync(cntb, 0, (size_t)NB * NN * 4, stream);
    k_countP<<<NB, 1024, 0, stream>>>(dstp, cntb, rank);
    k_merge<<<(NN + 255) / 256, 256, 0, stream>>>(cntb, cnt, NN);
    k_scanA<<<nb, 256, 0, stream>>>(cnt, rowptr, bsums, dinv, NN);
    k_scanB<<<1, 256, 0, stream>>>(bsums, nb);
    k_scanC<<<(NN + 255) / 256, 256, 0, stream>>>(rowptr, bsums, NN, NE);
    k_fillP<<<(ne4 + 255) / 256, 256, 0, stream>>>(srcp, dstp, rank, rowptr, cntb, csr_src, ne4);
  } else {
    hipMemsetAsync(cnt, 0, (size_t)NN * 4, stream);
    k_count<<<(ne4 + 255) / 256, 256, 0, stream>>>(dstp, cnt, rank, ne4);
    k_scanA<<<nb, 256, 0, stream>>>(cnt, rowptr, bsums, dinv, NN);
    k_scanB<<<1, 256, 0, stream>>>(bsums, nb);
    k_scanC<<<(NN + 255) / 256, 256, 0, stream>>>(rowptr, bsums, NN, NE);
    k_fill<<<(ne4 + 255) / 256, 256, 0, stream>>>(srcp, dstp, rank, rowptr, csr_src, ne4);
  }
  (void)base_need;

  k_gemm1<<<(NN + 63) / 64, 256, 0, stream>>>(x, W1, h1, NN);
  const int nwaves1 = (NN + 2) / 3;            // 3 nodes per wave
  k_agg40<<<(nwaves1 + 3) / 4, 256, 0, stream>>>(h1, rowptr, csr_src, dinv, b1, t1, NN);
  k_gemm2<<<(NN + 255) / 256, 256, 0, stream>>>(t1, W2, g2, NN);
  const int nwaves2 = (NN + 5) / 6;            // 6 nodes per wave
  k_agg20<<<(nwaves2 + 3) / 4, 256, 0, stream>>>(g2, rowptr, csr_src, dinv, b2, out, NN);
}

// Round 13
// 688.991 us; speedup vs baseline: 1.2157x; 1.2157x over previous
//
#include <hip/hip_runtime.h>
#include <cstddef>

// Problem constants (from reference setup_inputs)
static constexpr int NN   = 100000;   // nodes
static constexpr int NE   = 3200000;  // edges
static constexpr int CIN  = 512;
static constexpr int CHID = 40;
static constexpr int COUT = 20;

// LDS-histogram CSR build geometry
static constexpr int NCH    = 32;            // edge chunks
static constexpr int CHUNK_E = NE / NCH;     // 100000 edges per chunk (div by 4)
static constexpr int NRANGE = 8;             // node ranges
static constexpr int RANGE  = NN / NRANGE;   // 12500 nodes -> 50 KB LDS histogram

// clang native vector type: required by __builtin_nontemporal_load
// (HIP float4 is a class type and is rejected -- R9 compile error).
typedef float f32x4 __attribute__((ext_vector_type(4)));

// ---------------- CSR build (LDS histograms; NO memory-side atomics) ----------------
// R12 lesson: global-memory atomics execute at the TCC regardless of scope
// (WRITE_SIZE 112.3MB identical for device-scope and workgroup-scope) --
// 3.2M atomics = ~102MB of 32B memory-side transactions, ~150-167us floor.
// Only LDS atomics avoid that path. Block (c,r) owns edge-chunk c and node-
// range r: coalesced chunk read, ds_add histogram, coalesced count writeout.

__global__ __launch_bounds__(1024) void k_histA(const int* __restrict__ dst,
                                                int* __restrict__ cntb) {
  __shared__ int hc[RANGE];  // 50 KB
  const int c  = blockIdx.x >> 3;    // chunk 0..31
  const int r0 = (blockIdx.x & 7) * RANGE;
  for (int i = threadIdx.x; i < RANGE; i += 1024) hc[i] = 0;
  __syncthreads();
  const int base = c * (CHUNK_E / 4);
  const int end  = base + CHUNK_E / 4;
  for (int i = base + (int)threadIdx.x; i < end; i += 1024) {
    const int4 d = ((const int4*)dst)[i];
    if ((unsigned)(d.x - r0) < (unsigned)RANGE) atomicAdd(&hc[d.x - r0], 1);
    if ((unsigned)(d.y - r0) < (unsigned)RANGE) atomicAdd(&hc[d.y - r0], 1);
    if ((unsigned)(d.z - r0) < (unsigned)RANGE) atomicAdd(&hc[d.z - r0], 1);
    if ((unsigned)(d.w - r0) < (unsigned)RANGE) atomicAdd(&hc[d.w - r0], 1);
  }
  __syncthreads();
  int* __restrict__ outp = cntb + (size_t)c * NN + r0;
  for (int i = threadIdx.x; i < RANGE; i += 1024) outp[i] = hc[i];
}

// per node: exclusive prefix across the 32 chunk-copies (in place) + total.
__global__ __launch_bounds__(256) void k_merge(int* __restrict__ cntb, int* __restrict__ cnt, int n) {
  const int i = blockIdx.x * 256 + threadIdx.x;
  if (i >= n) return;
  int s = 0;
#pragma unroll 8
  for (int b = 0; b < NCH; ++b) {
    int* p = cntb + (size_t)b * NN + i;
    const int t = *p;
    *p = s;
    s += t;
  }
  cnt[i] = s;
}

// block of 256 scans 1024 elements; writes per-element exclusive scan (within block),
// block totals, and fused dinv = rsqrt(deg) = rsqrt(cnt+1).
__global__ __launch_bounds__(256) void k_scanA(const int* __restrict__ cnt, int* __restrict__ excl,
                                               int* __restrict__ bsums, float* __restrict__ dinv, int n) {
  __shared__ int sdata[256];
  const int t = threadIdx.x;
  const int base = blockIdx.x * 1024 + t * 4;
  int v[4];
#pragma unroll
  for (int j = 0; j < 4; ++j) {
    const int i = base + j;
    v[j] = (i < n) ? cnt[i] : 0;
    if (i < n) dinv[i] = rsqrtf((float)(v[j] + 1));
  }
  const int s4 = v[0] + v[1] + v[2] + v[3];
  sdata[t] = s4;
  __syncthreads();
  for (int off = 1; off < 256; off <<= 1) {
    int val = 0;
    if (t >= off) val = sdata[t - off];
    __syncthreads();
    sdata[t] += val;
    __syncthreads();
  }
  int run = sdata[t] - s4;  // exclusive prefix of this thread's 4 items
#pragma unroll
  for (int j = 0; j < 4; ++j) {
    const int i = base + j;
    if (i < n) excl[i] = run;
    run += v[j];
  }
  if (t == 255) bsums[blockIdx.x] = sdata[255];
}

__global__ __launch_bounds__(256) void k_scanB(int* __restrict__ bsums, int nb) {
  __shared__ int sdata[256];
  const int t = threadIdx.x;
  const int v = (t < nb) ? bsums[t] : 0;
  sdata[t] = v;
  __syncthreads();
  for (int off = 1; off < 256; off <<= 1) {
    int val = 0;
    if (t >= off) val = sdata[t - off];
    __syncthreads();
    sdata[t] += val;
    __syncthreads();
  }
  if (t < nb) bsums[t] = sdata[t] - v;  // exclusive, in place
}

__global__ __launch_bounds__(256) void k_scanC(int* __restrict__ rowptr, const int* __restrict__ boff,
                                               int n, int n_edges) {
  const int i = blockIdx.x * 256 + threadIdx.x;
  if (i < n) rowptr[i] += boff[i >> 10];
  if (i == 0) rowptr[n] = n_edges;
}

// Pass B: re-read chunk, re-run the LDS histogram to assign local ranks,
// place edges: pos = rowptr[d] + cntb[c][d] (cross-chunk offset) + lds_rank.
// No replay-order equivalence needed: pass A produced only COUNTS; bucket
// order has always been arbitrary (R11 atomic races were too).
__global__ __launch_bounds__(1024) void k_histFill(const int* __restrict__ src,
                                                   const int* __restrict__ dst,
                                                   const int* __restrict__ rowptr,
                                                   const int* __restrict__ cntb,
                                                   int* __restrict__ csr_src) {
  __shared__ int hc[RANGE];  // 50 KB
  const int c  = blockIdx.x >> 3;
  const int r0 = (blockIdx.x & 7) * RANGE;
  for (int i = threadIdx.x; i < RANGE; i += 1024) hc[i] = 0;
  __syncthreads();
  const int* __restrict__ cbo = cntb + (size_t)c * NN;
  const int base = c * (CHUNK_E / 4);
  const int end  = base + CHUNK_E / 4;
  for (int i = base + (int)threadIdx.x; i < end; i += 1024) {
    const int4 d = ((const int4*)dst)[i];
    const int4 s = ((const int4*)src)[i];
    if ((unsigned)(d.x - r0) < (unsigned)RANGE) {
      const int rk = atomicAdd(&hc[d.x - r0], 1);
      csr_src[rowptr[d.x] + cbo[d.x] + rk] = s.x;
    }
    if ((unsigned)(d.y - r0) < (unsigned)RANGE) {
      const int rk = atomicAdd(&hc[d.y - r0], 1);
      csr_src[rowptr[d.y] + cbo[d.y] + rk] = s.y;
    }
    if ((unsigned)(d.z - r0) < (unsigned)RANGE) {
      const int rk = atomicAdd(&hc[d.z - r0], 1);
      csr_src[rowptr[d.z] + cbo[d.z] + rk] = s.z;
    }
    if ((unsigned)(d.w - r0) < (unsigned)RANGE) {
      const int rk = atomicAdd(&hc[d.w - r0], 1);
      csr_src[rowptr[d.w] + cbo[d.w] + rk] = s.w;
    }
  }
}

// ---------------- GEMM 1: exact R11 version (measured 147us, absmax 4.88e-4) ----------------
// NT loads (WRITE 215.6 -> 15.6MB confirmed R11); R12's software-pipeline
// edit is dropped (implicated in ~+20us; never validated in isolation).
__global__ __launch_bounds__(256) void k_gemm1(const float* __restrict__ x, const float* __restrict__ W,
                                               float* __restrict__ h, int n) {
  __shared__ float xt[64 * 128];  // 32 KB; reused as output staging [64][44]
  const int t  = threadIdx.x;
  const int nd = t & 63;                                   // node-in-tile (compute)
  const int g  = __builtin_amdgcn_readfirstlane(t >> 6);   // channel group 0..3 (wave-uniform)
  const int block0 = blockIdx.x * 64;

  // staging map: idx = r*256 + t -> row = idx>>5, float4-col = idx&31
  const int sn = t >> 5;   // rows sn, sn+8, ..., sn+56
  const int c4 = t & 31;

  float acc[10];
#pragma unroll
  for (int j = 0; j < 10; ++j) acc[j] = 0.f;

  for (int kt = 0; kt < 4; ++kt) {
    // ---- issue coalesced NT staging loads (before barrier: overlap other waves)
    f32x4 v[8];
#pragma unroll
    for (int r = 0; r < 8; ++r) {
      const int row = r * 8 + sn;
      int gn = block0 + row;
      if (gn >= n) gn = n - 1;  // clamp: valid memory, store is guarded
      v[r] = __builtin_nontemporal_load(
          ((const f32x4*)(x + (size_t)gn * CIN + kt * 128)) + c4);
    }
    if (kt) __syncthreads();  // previous tile fully consumed
#pragma unroll
    for (int r = 0; r < 8; ++r) {
      const int row = r * 8 + sn;
      const int byte = row * 512 + ((c4 * 16) ^ ((row & 31) << 4));
      *(f32x4*)((char*)xt + byte) = v[r];
    }
    __syncthreads();          // tile ready

    // ---- compute: 128 k-values, 10 channels per thread
    const float* __restrict__ Wg = W + (size_t)kt * 128 * CHID + g * 10;
#pragma unroll 4
    for (int k4 = 0; k4 < 32; ++k4) {
      const int byte = nd * 512 + ((k4 * 16) ^ ((nd & 31) << 4));
      const f32x4 xv = *(const f32x4*)((const char*)xt + byte);
      const float* __restrict__ Wk = Wg + k4 * 4 * CHID;
#pragma unroll
      for (int j = 0; j < 10; ++j) acc[j] = fmaf(xv.x, Wk[j], acc[j]);
#pragma unroll
      for (int j = 0; j < 10; ++j) acc[j] = fmaf(xv.y, Wk[CHID + j], acc[j]);
#pragma unroll
      for (int j = 0; j < 10; ++j) acc[j] = fmaf(xv.z, Wk[2 * CHID + j], acc[j]);
#pragma unroll
      for (int j = 0; j < 10; ++j) acc[j] = fmaf(xv.w, Wk[3 * CHID + j], acc[j]);
    }
  }

  // ---- coalesced epilogue through LDS ----
  __syncthreads();  // all waves done reading xt
#pragma unroll
  for (int j = 0; j < 10; ++j) xt[nd * 44 + g * 10 + j] = acc[j];
  __syncthreads();
  // 64 rows x 40 floats = 640 float4, contiguous across the block's h region
  for (int i = t; i < 640; i += 256) {
    const int row = i / 10;
    const int c   = i % 10;
    const int node = block0 + row;
    if (node < n)
      ((float4*)(h + (size_t)node * CHID))[c] = *(const float4*)&xt[row * 44 + c * 4];
  }
}

__global__ __launch_bounds__(256) void k_gemm2(const float* __restrict__ t1, const float* __restrict__ W,
                                               float* __restrict__ g, int n) {
  const int node = blockIdx.x * 256 + threadIdx.x;
  if (node >= n) return;
  const float4* __restrict__ r4 = (const float4*)(t1 + (size_t)node * CHID);
  float acc[COUT];
#pragma unroll
  for (int c = 0; c < COUT; ++c) acc[c] = 0.f;
#pragma unroll
  for (int kk = 0; kk < CHID / 4; ++kk) {
    const float4 xv = r4[kk];
    const float* __restrict__ Wk = W + kk * 4 * COUT;
#pragma unroll
    for (int c = 0; c < COUT; ++c) {
      float a = acc[c];
      a = fmaf(xv.x, Wk[c], a);
      a = fmaf(xv.y, Wk[COUT + c], a);
      a = fmaf(xv.z, Wk[2 * COUT + c], a);
      a = fmaf(xv.w, Wk[3 * COUT + c], a);
      acc[c] = a;
    }
  }
  float* __restrict__ o = g + (size_t)node * COUT;
#pragma unroll
  for (int c = 0; c < COUT; ++c) o[c] = acc[c];
}

// ---------------- CSR aggregation ----------------
// Layer 1 (CH=40): float2 channel-packing — 20 lanes/node, 3 nodes/wave.
__global__ __launch_bounds__(256) void k_agg40(const float* __restrict__ h, const int* __restrict__ rowptr,
                                               const int* __restrict__ csr_src, const float* __restrict__ dinv,
                                               const float* __restrict__ bias, float* __restrict__ out, int n) {
  const int wave = (blockIdx.x * 256 + (int)threadIdx.x) >> 6;
  const int lane = threadIdx.x & 63;
  const int sub  = lane / 20;   // 0..2 active; 3 => idle lanes 60..63
  const int cp   = lane % 20;   // channel pair: channels {2cp, 2cp+1}
  const int node = wave * 3 + sub;
  if (sub >= 3 || node >= n) return;
  const float2* __restrict__ h2 = (const float2*)h;
  const int r0 = rowptr[node];
  const int r1 = rowptr[node + 1];
  const float dv = dinv[node];
  const float self_w = dv * dv;  // self-loop norm = 1/deg
  float2 acc = h2[(size_t)node * 20 + cp];
  acc.x *= self_w;
  acc.y *= self_w;
  int i = r0;
  for (; i + 4 <= r1; i += 4) {
    const int s0 = csr_src[i + 0];
    const int s1 = csr_src[i + 1];
    const int s2 = csr_src[i + 2];
    const int s3 = csr_src[i + 3];
    const float w0 = dinv[s0] * dv;
    const float w1 = dinv[s1] * dv;
    const float w2 = dinv[s2] * dv;
    const float w3 = dinv[s3] * dv;
    const float2 g0 = h2[(size_t)s0 * 20 + cp];
    const float2 g1 = h2[(size_t)s1 * 20 + cp];
    const float2 g2 = h2[(size_t)s2 * 20 + cp];
    const float2 g3 = h2[(size_t)s3 * 20 + cp];
    acc.x = fmaf(g0.x, w0, acc.x); acc.y = fmaf(g0.y, w0, acc.y);
    acc.x = fmaf(g1.x, w1, acc.x); acc.y = fmaf(g1.y, w1, acc.y);
    acc.x = fmaf(g2.x, w2, acc.x); acc.y = fmaf(g2.y, w2, acc.y);
    acc.x = fmaf(g3.x, w3, acc.x); acc.y = fmaf(g3.y, w3, acc.y);
  }
  for (; i < r1; ++i) {
    const int s = csr_src[i];
    const float w = dinv[s] * dv;
    const float2 g = h2[(size_t)s * 20 + cp];
    acc.x = fmaf(g.x, w, acc.x);
    acc.y = fmaf(g.y, w, acc.y);
  }
  const float2 bv = ((const float2*)bias)[cp];
  float2 v;
  v.x = fmaxf(acc.x + bv.x, 0.f);  // ReLU (layer 1 only)
  v.y = fmaxf(acc.y + bv.y, 0.f);
  ((float2*)out)[(size_t)node * 20 + cp] = v;
}

// Layer 2 (CH=20): float2 packing — 10 lanes/node, 6 nodes/wave.
__global__ __launch_bounds__(256) void k_agg20(const float* __restrict__ h, const int* __restrict__ rowptr,
                                               const int* __restrict__ csr_src, const float* __restrict__ dinv,
                                               const float* __restrict__ bias, float* __restrict__ out, int n) {
  const int wave = (blockIdx.x * 256 + (int)threadIdx.x) >> 6;
  const int lane = threadIdx.x & 63;
  const int sub  = lane / 10;   // 0..5 active; 6 => idle lanes 60..63
  const int cp   = lane % 10;   // channel pair: channels {2cp, 2cp+1}
  const int node = wave * 6 + sub;
  if (sub >= 6 || node >= n) return;
  const float2* __restrict__ h2 = (const float2*)h;
  const int r0 = rowptr[node];
  const int r1 = rowptr[node + 1];
  const float dv = dinv[node];
  const float self_w = dv * dv;
  float2 acc = h2[(size_t)node * 10 + cp];
  acc.x *= self_w;
  acc.y *= self_w;
  int i = r0;
  for (; i + 4 <= r1; i += 4) {
    const int s0 = csr_src[i + 0];
    const int s1 = csr_src[i + 1];
    const int s2 = csr_src[i + 2];
    const int s3 = csr_src[i + 3];
    const float w0 = dinv[s0] * dv;
    const float w1 = dinv[s1] * dv;
    const float w2 = dinv[s2] * dv;
    const float w3 = dinv[s3] * dv;
    const float2 g0 = h2[(size_t)s0 * 10 + cp];
    const float2 g1 = h2[(size_t)s1 * 10 + cp];
    const float2 g2 = h2[(size_t)s2 * 10 + cp];
    const float2 g3 = h2[(size_t)s3 * 10 + cp];
    acc.x = fmaf(g0.x, w0, acc.x); acc.y = fmaf(g0.y, w0, acc.y);
    acc.x = fmaf(g1.x, w1, acc.x); acc.y = fmaf(g1.y, w1, acc.y);
    acc.x = fmaf(g2.x, w2, acc.x); acc.y = fmaf(g2.y, w2, acc.y);
    acc.x = fmaf(g3.x, w3, acc.x); acc.y = fmaf(g3.y, w3, acc.y);
  }
  for (; i < r1; ++i) {
    const int s = csr_src[i];
    const float w = dinv[s] * dv;
    const float2 g = h2[(size_t)s * 10 + cp];
    acc.x = fmaf(g.x, w, acc.x);
    acc.y = fmaf(g.y, w, acc.y);
  }
  const float2 bv = ((const float2*)bias)[cp];
  float2 v;
  v.x = acc.x + bv.x;
  v.y = acc.y + bv.y;
  ((float2*)out)[(size_t)node * 10 + cp] = v;
}

// ---------------- launch ----------------

extern "C" void kernel_launch(void* const* d_in, const int* in_sizes, int n_in,
                              void* d_out, int out_size, void* d_ws, size_t ws_size,
                              hipStream_t stream) {
  const float* x   = (const float*)d_in[0];
  const int*   ei  = (const int*)d_in[1];
  const float* W1  = (const float*)d_in[2];
  const float* b1  = (const float*)d_in[3];
  const float* W2  = (const float*)d_in[4];
  const float* b2  = (const float*)d_in[5];
  float* out = (float*)d_out;

  const int* srcp = ei;        // edge_index[0]
  const int* dstp = ei + NE;   // edge_index[1]

  // workspace layout (~59 MB; rank[] eliminated, cntb 12.8MB added)
  char* ws = (char*)d_ws;
  size_t off = 0;
  auto take = [&](size_t bytes) -> char* {
    char* p = ws + off;
    off = (off + bytes + 255) & ~(size_t)255;
    return p;
  };
  int*   cnt     = (int*)take((size_t)NN * 4);
  int*   rowptr  = (int*)take((size_t)(NN + 1) * 4);
  float* dinv    = (float*)take((size_t)NN * 4);
  int*   bsums   = (int*)take(256 * 4);
  int*   cntb    = (int*)take((size_t)NCH * NN * 4);  // 12.8 MB chunk histograms
  int*   csr_src = (int*)take((size_t)NE * 4);
  float* h1      = (float*)take((size_t)NN * CHID * 4);
  float* t1      = (float*)take((size_t)NN * CHID * 4);
  float* g2      = h1;  // h1 dead after agg1; reuse for layer-2 GEMM output

  (void)in_sizes; (void)n_in; (void)out_size; (void)ws_size;

  const int nb = (NN + 1023) / 1024;  // 98

  k_histA<<<NCH * NRANGE, 1024, 0, stream>>>(dstp, cntb);
  k_merge<<<(NN + 255) / 256, 256, 0, stream>>>(cntb, cnt, NN);
  k_scanA<<<nb, 256, 0, stream>>>(cnt, rowptr, bsums, dinv, NN);
  k_scanB<<<1, 256, 0, stream>>>(bsums, nb);
  k_scanC<<<(NN + 255) / 256, 256, 0, stream>>>(rowptr, bsums, NN, NE);
  k_histFill<<<NCH * NRANGE, 1024, 0, stream>>>(srcp, dstp, rowptr, cntb, csr_src);

  k_gemm1<<<(NN + 63) / 64, 256, 0, stream>>>(x, W1, h1, NN);
  const int nwaves1 = (NN + 2) / 3;            // 3 nodes per wave
  k_agg40<<<(nwaves1 + 3) / 4, 256, 0, stream>>>(h1, rowptr, csr_src, dinv, b1, t1, NN);
  k_gemm2<<<(NN + 255) / 256, 256, 0, stream>>>(t1, W2, g2, NN);
  const int nwaves2 = (NN + 5) / 6;            // 6 nodes per wave
  k_agg20<<<(nwaves2 + 3) / 4, 256, 0, stream>>>(g2, rowptr, csr_src, dinv, b2, out, NN);
}